// Round 7
// baseline (964.460 us; speedup 1.0000x reference)
//
#include <hip/hip_runtime.h>
#include <hip/hip_bf16.h>
#include <math.h>

#define B_ 2
#define S_ 2048
#define D_ 2048
#define H_ 16
#define HD_ 128
#define NT_ (B_*S_)
#define GS_ 0.1f
#define LOG2E_ 1.4426950408889634f

typedef _Float16 half8 __attribute__((__vector_size__(16)));
typedef _Float16 half4v __attribute__((__vector_size__(8)));
typedef _Float16 half2v __attribute__((__vector_size__(4)));
typedef float f32x4 __attribute__((__vector_size__(16)));
typedef float f32x16 __attribute__((__vector_size__(64)));

#define VMCNT(n) asm volatile("s_waitcnt vmcnt(" #n ")" ::: "memory")
#define LGKMCNT0 asm volatile("s_waitcnt lgkmcnt(0)" ::: "memory")

__device__ __forceinline__ void gload_lds16(const void* g, void* s) {
  __builtin_amdgcn_global_load_lds(
      (const __attribute__((address_space(1))) unsigned int*)g,
      (__attribute__((address_space(3))) unsigned int*)s, 16, 0, 0);
}

// ---------------- prep kernels ----------------

__global__ void cvt_f32_to_f16(const float* __restrict__ in, _Float16* __restrict__ out, int n4) {
  int i = blockIdx.x * blockDim.x + threadIdx.x;
  if (i >= n4) return;
  float4 v = ((const float4*)in)[i];
  half4v o = { (_Float16)v.x, (_Float16)v.y, (_Float16)v.z, (_Float16)v.w };
  ((half4v*)out)[i] = o;
}

// out[c][r] = (f16) in[r][c]   (in: R x C fp32 row-major)
__global__ void transpose_to_f16(const float* __restrict__ in, _Float16* __restrict__ out, int R, int C) {
  __shared__ float t[32][33];
  int c0 = blockIdx.x*32, r0 = blockIdx.y*32;
  int tx = threadIdx.x, ty = threadIdx.y;
#pragma unroll
  for (int j = 0; j < 32; j += 8)
    t[ty+j][tx] = in[(size_t)(r0+ty+j)*C + c0+tx];
  __syncthreads();
#pragma unroll
  for (int j = 0; j < 32; j += 8)
    out[(size_t)(c0+ty+j)*R + r0+tx] = (_Float16)t[tx][ty+j];
}

__global__ void prep_tables(const float* __restrict__ mw, float* __restrict__ cost,
                            float* __restrict__ sint, float* __restrict__ lmw) {
  int t = blockIdx.x*256 + threadIdx.x;
  if (t < S_*64) {
    int s = t >> 6, d = t & 63;
    float inv = (float)pow(10000.0, -(double)(2*d)/(double)HD_);
    float f = (float)s * inv;
    cost[t] = cosf(f);
    sint[t] = sinf(f);
  }
  // pre-scaled by log2e (consumed only by attn, which works in exp2 domain)
  if (t < B_*S_) lmw[t] = log1pf(mw[t]*GS_ + 1e-8f) * LOG2E_;
}

// ---------------- GEMM (R1 structure, 128x128, 4 waves, 3-4 blocks/CU) ----------------

template<bool F32OUT>
__global__ __launch_bounds__(256) void gemm_f16(
    const _Float16* __restrict__ A, const _Float16* __restrict__ Bt,
    void* __restrict__ Cout, const float* __restrict__ bias,
    int M, int N, int K)
{
  __shared__ __align__(16) _Float16 As[128*64];
  __shared__ __align__(16) _Float16 Bs[128*64];
  int n0 = blockIdx.x*128, m0 = blockIdx.y*128;
  int tid = threadIdx.x;
  int w = tid >> 6, l = tid & 63;
  int lhi = l >> 4, llo = l & 15;
  int wr = w >> 1, wc = w & 1;
  const f32x4 fz = {0.f,0.f,0.f,0.f};
  f32x4 acc[4][4];
#pragma unroll
  for (int i = 0; i < 4; ++i)
#pragma unroll
    for (int j = 0; j < 4; ++j) acc[i][j] = fz;

  for (int kt = 0; kt < K; kt += 64) {
#pragma unroll
    for (int i = 0; i < 4; ++i) {
      int sid = i*256 + tid;
      int row = sid >> 3;
      int c   = (sid & 7) ^ (row & 7);
      gload_lds16(A  + (size_t)(m0+row)*K + kt + c*8, (char*)As + (size_t)(i*256 + w*64)*16);
      gload_lds16(Bt + (size_t)(n0+row)*K + kt + c*8, (char*)Bs + (size_t)(i*256 + w*64)*16);
    }
    __syncthreads();
#pragma unroll
    for (int kk = 0; kk < 2; ++kk) {
      half8 a[4], b[4];
#pragma unroll
      for (int mi = 0; mi < 4; ++mi) {
        int row = wr*64 + mi*16 + llo;
        int ch = (kk*4 + lhi) ^ (row & 7);
        a[mi] = *(const half8*)((const char*)As + row*128 + ch*16);
      }
#pragma unroll
      for (int ni = 0; ni < 4; ++ni) {
        int row = wc*64 + ni*16 + llo;
        int ch = (kk*4 + lhi) ^ (row & 7);
        b[ni] = *(const half8*)((const char*)Bs + row*128 + ch*16);
      }
#pragma unroll
      for (int mi = 0; mi < 4; ++mi)
#pragma unroll
        for (int ni = 0; ni < 4; ++ni)
          acc[mi][ni] = __builtin_amdgcn_mfma_f32_16x16x32_f16(a[mi], b[ni], acc[mi][ni], 0, 0, 0);
    }
    __syncthreads();
  }
#pragma unroll
  for (int mi = 0; mi < 4; ++mi)
#pragma unroll
    for (int ni = 0; ni < 4; ++ni)
#pragma unroll
      for (int r = 0; r < 4; ++r) {
        int row = m0 + wr*64 + mi*16 + lhi*4 + r;
        int col = n0 + wc*64 + ni*16 + llo;
        if constexpr (F32OUT)
          ((float*)Cout)[(size_t)row*N + col] = acc[mi][ni][r] + bias[col];
        else
          ((_Float16*)Cout)[(size_t)row*N + col] = (_Float16)acc[mi][ni][r];
      }
}

// ---------------- RoPE + head reorder for Q,K ----------------
__global__ void rope_qk(const _Float16* __restrict__ qkv, const float* __restrict__ cost,
                        const float* __restrict__ sint, _Float16* __restrict__ Qr,
                        _Float16* __restrict__ Kr) {
  int token = blockIdx.x;
  int b = token >> 11, s = token & (S_-1);
  int t = threadIdx.x;
  int isk = t >> 7, u = t & 127;
  int hh = u >> 3, dd0 = (u & 7)*8;
  const _Float16* src = qkv + (size_t)token*(3*D_) + (size_t)isk*D_ + hh*128;
  half8 a  = *(const half8*)(src + dd0);
  half8 bb = *(const half8*)(src + 64 + dd0);
  half8 lo, hi;
#pragma unroll
  for (int j = 0; j < 8; ++j) {
    float c  = cost[s*64 + dd0 + j];
    float sn = sint[s*64 + dd0 + j];
    float x1 = (float)a[j], x2 = (float)bb[j];
    lo[j] = (_Float16)(x1*c - x2*sn);
    hi[j] = (_Float16)(x2*c + x1*sn);
  }
  _Float16* dst = (isk ? Kr : Qr) + ((size_t)(b*H_ + hh)*S_ + s)*HD_;
  *(half8*)(dst + dd0) = lo;
  *(half8*)(dst + 64 + dd0) = hi;
}

// ---------------- V transpose: qkv v-part -> Vt[b,h,d,s] ----------------
__global__ void v_transpose(const _Float16* __restrict__ qkv, _Float16* __restrict__ Vt) {
  __shared__ _Float16 tile[64][33];
  int st = blockIdx.x*64;
  int dt = blockIdx.y*32;
  int bh = blockIdx.z;
  int b = bh >> 4, h = bh & 15;
  int t = threadIdx.x;
  int s = t >> 2, dc = (t & 3)*8;
  half8 v = *(const half8*)(qkv + (size_t)(b*S_ + st + s)*(3*D_) + 2*D_ + h*128 + dt + dc);
#pragma unroll
  for (int j = 0; j < 8; ++j) tile[s][dc+j] = v[j];
  __syncthreads();
  int d = t >> 3, sc = (t & 7)*8;
  half8 o;
#pragma unroll
  for (int j = 0; j < 8; ++j) o[j] = tile[sc+j][d];
  *(half8*)(Vt + ((size_t)bh*HD_ + dt + d)*S_ + st + sc) = o;
}

// ---------------- flash attention: 4 waves x 32 q-rows, 32x32x16 MFMA ----------------
// R7: R5 structure + 64KB LDS (K dbuf 2x16K @0; V single 16K @32768; bias
// 4x4K @49152) -> 2 blocks/CU; NO launch_bounds cap, NO cross-tile bias
// register prefetch (R6's spill source). One VMCNT(0) gate per tile: issue
// K(t+1) -> bias(t) -> V(t), gate after QK^T (bias+V needed there; K(t+1)
// has a full tile of slack). Masked wave-tiles skip compute+bias loads.
// exp2 domain (log2e folded into Q scale, GS, lmw table).
__global__ void attn_kernel(
    const _Float16* __restrict__ Qr, const _Float16* __restrict__ Kr,
    const _Float16* __restrict__ Vt, const float* __restrict__ policy,
    const float* __restrict__ lmw, _Float16* __restrict__ Ob)
{
  __shared__ __align__(16) char SMEM[65536];
  int bx = blockIdx.x;
  int qb = (S_/128) - 1 - (bx / (B_*H_));   // heavy tiles first
  int rem = bx % (B_*H_);
  int h = rem >> 1;
  int b = rem & 1;                          // b fastest -> policy L3 reuse
  int bh = b*H_ + h;
  const _Float16* Qb = Qr + (size_t)bh*S_*HD_;
  const _Float16* Kb = Kr + (size_t)bh*S_*HD_;
  const _Float16* Vb = Vt + (size_t)bh*HD_*S_;
  const float* pol = policy + (size_t)h*S_*S_;
  const float* lmb = lmw + b*S_;
  int tid = threadIdx.x;
  int w = tid >> 6, l = tid & 63;
  int l31 = l & 31, lh = l >> 5;
  int r8 = l >> 3, c8 = l & 7;
  int q0 = qb*128 + w*32;
  int gq = q0 + l31;
  char* Bw = SMEM + 49152 + w*4096;   // per-wave bias [g 0..15][q 0..31] 8B

  auto stageK = [&](int tt){
    char* dstb = SMEM + (size_t)(tt&1)*16384;
    int kv = tt*64;
#pragma unroll
    for (int i = 0; i < 4; ++i) {
      int sid = i*256 + tid;
      int krow = sid >> 4;
      int ck = (sid & 15) ^ (krow & 15);
      gload_lds16(Kb + (size_t)(kv+krow)*HD_ + ck*8, dstb + (size_t)(i*256 + w*64)*16);
    }
  };
  auto stageV = [&](int tt){
    char* dstb = SMEM + 32768;
    int kv = tt*64;
#pragma unroll
    for (int i = 0; i < 4; ++i) {
      int sid = i*256 + tid;
      int krow = sid >> 4;
      int ck = (sid & 15) ^ (krow & 15);
      int dv = krow*2 + (ck >> 3);
      gload_lds16(Vb + (size_t)dv*S_ + kv + (ck & 7)*8, dstb + (size_t)(i*256 + w*64)*16);
    }
  };

  const float qscale = 0.08838834764831845f * LOG2E_;  // 1/sqrt(128) * log2e
  half8 qf[8];
#pragma unroll
  for (int ds = 0; ds < 8; ++ds) {
    half8 qv = *(const half8*)(Qb + (size_t)gq*HD_ + ds*16 + lh*8);
#pragma unroll
    for (int e = 0; e < 8; ++e) qv[e] = (_Float16)((float)qv[e] * qscale);
    qf[ds] = qv;
  }

  f32x16 oacc[4];
#pragma unroll
  for (int i = 0; i < 4; ++i)
#pragma unroll
    for (int r = 0; r < 16; ++r) oacc[i][r] = 0.f;
  float m_ = -INFINITY, l_ = 0.f;
  const float GS2 = GS_ * LOG2E_;
  int nt = qb*2 + 2;

  // prologue: K(0)
  stageK(0);
  VMCNT(0);
  __builtin_amdgcn_sched_barrier(0);
  __builtin_amdgcn_s_barrier();

  for (int t = 0; t < nt; ++t) {
    int kv0 = t*64;
    const char* Kbase = SMEM + (size_t)(t&1)*16384;
    const char* Vbase = SMEM + 32768;
    bool pre = (t+1 < nt);
    bool act = (kv0 <= q0 + 31);

    // ---- issue: K(t+1), bias(t) (reg), V(t)
    if (pre) stageK(t+1);
    float4 pb[4][2], lm[2];
    if (act) {
#pragma unroll
      for (int ci = 0; ci < 2; ++ci) {
        lm[ci] = *(const float4*)(lmb + kv0 + ci*32 + c8*4);
#pragma unroll
        for (int ri = 0; ri < 4; ++ri)
          pb[ri][ci] = *(const float4*)(pol + (size_t)(q0 + ri*8 + r8)*S_ + kv0 + ci*32 + c8*4);
      }
    }
    stageV(t);

    // ---- S^T = mfma(K, Q): sacc[kh] covers k in [kh*32, +32), q = l31
    f32x16 sacc[2];
    if (act) {
#pragma unroll
      for (int kh = 0; kh < 2; ++kh)
#pragma unroll
        for (int r = 0; r < 16; ++r) sacc[kh][r] = 0.f;
      __builtin_amdgcn_s_setprio(1);
#pragma unroll
      for (int kh = 0; kh < 2; ++kh) {
        const char* kbase = Kbase + (kh*32 + l31)*256;
        int sw = l31 & 15;
#pragma unroll
        for (int ds = 0; ds < 8; ++ds) {
          half8 kf = *(const half8*)(kbase + (((ds*2 + lh) ^ sw) << 4));
          sacc[kh] = __builtin_amdgcn_mfma_f32_32x32x16_f16(kf, qf[ds], sacc[kh], 0, 0, 0);
        }
      }
      __builtin_amdgcn_s_setprio(0);
    }

    // ---- single gate: bias regs + V ready (K(t+1) drained early, harmless)
    VMCNT(0);
    __builtin_amdgcn_sched_barrier(0);

    if (act) {
      // bias build -> wave-private LDS [g][q], write ~4-way, read 2-way
#pragma unroll
      for (int ci = 0; ci < 2; ++ci)
#pragma unroll
        for (int ri = 0; ri < 4; ++ri) {
          float bx_ = fmaf(pb[ri][ci].x, GS2, lm[ci].x);
          float by_ = fmaf(pb[ri][ci].y, GS2, lm[ci].y);
          float bz_ = fmaf(pb[ri][ci].z, GS2, lm[ci].z);
          float bw_ = fmaf(pb[ri][ci].w, GS2, lm[ci].w);
          half2v h0 = __builtin_amdgcn_cvt_pkrtz(bx_, by_);
          half2v h1 = __builtin_amdgcn_cvt_pkrtz(bz_, bw_);
          half4v o4 = { h0[0], h0[1], h1[0], h1[1] };
          int g = ci*8 + c8;
          *(half4v*)(Bw + g*256 + (((ri*8 + r8) ^ (2*g)) & 31)*8) = o4;
        }
      LGKMCNT0;
      __builtin_amdgcn_sched_barrier(0);

      bool domask = (kv0 + 63 > q0);
#pragma unroll
      for (int kh = 0; kh < 2; ++kh)
#pragma unroll
        for (int rq = 0; rq < 4; ++rq) {
          int g = kh*8 + 2*rq + lh;
          half4v b4 = *(const half4v*)(Bw + g*256 + (((l31 ^ (2*g)) & 31)*8));
#pragma unroll
          for (int rm = 0; rm < 4; ++rm) {
            int r = rq*4 + rm;
            float v = sacc[kh][r] + (float)b4[rm];
            int gk = kv0 + kh*32 + rm + 8*rq + 4*lh;
            if (domask && gk > gq) v = -1e9f;
            sacc[kh][r] = v;
          }
        }

      float mx = -INFINITY;
#pragma unroll
      for (int kh = 0; kh < 2; ++kh)
#pragma unroll
        for (int r = 0; r < 16; ++r) mx = fmaxf(mx, sacc[kh][r]);
      mx = fmaxf(mx, __shfl_xor(mx, 32));
      bool skip = __all(mx - m_ <= 11.5f);   // defer-max (T13), log2 units
      if (!skip) {
        float mnew = fmaxf(m_, mx);
        float fct = exp2f(m_ - mnew);
        m_ = mnew;
        l_ *= fct;
#pragma unroll
        for (int i = 0; i < 4; ++i)
#pragma unroll
          for (int r = 0; r < 16; ++r) oacc[i][r] *= fct;
      }
      float rsum = 0.f;
#pragma unroll
      for (int kh = 0; kh < 2; ++kh)
#pragma unroll
        for (int r = 0; r < 16; ++r) {
          float pp = exp2f(sacc[kh][r] - m_);
          sacc[kh][r] = pp;
          rsum += pp;
        }
      rsum += __shfl_xor(rsum, 32);
      l_ += rsum;

      // P repack to fp16 PV B-fragments (in-register)
      half8 pfrag[4];
#pragma unroll
      for (int s = 0; s < 4; ++s) {
        int kh = s >> 1, rb = (s & 1)*8;
        unsigned A0 = __builtin_bit_cast(unsigned, __builtin_amdgcn_cvt_pkrtz(sacc[kh][rb+0], sacc[kh][rb+1]));
        unsigned A1 = __builtin_bit_cast(unsigned, __builtin_amdgcn_cvt_pkrtz(sacc[kh][rb+2], sacc[kh][rb+3]));
        unsigned B0 = __builtin_bit_cast(unsigned, __builtin_amdgcn_cvt_pkrtz(sacc[kh][rb+4], sacc[kh][rb+5]));
        unsigned B1 = __builtin_bit_cast(unsigned, __builtin_amdgcn_cvt_pkrtz(sacc[kh][rb+6], sacc[kh][rb+7]));
        unsigned sA0 = (unsigned)__shfl_xor((int)A0, 32);
        unsigned sA1 = (unsigned)__shfl_xor((int)A1, 32);
        unsigned sB0 = (unsigned)__shfl_xor((int)B0, 32);
        unsigned sB1 = (unsigned)__shfl_xor((int)B1, 32);
        uint4 uu;
        uu.x = lh ? sB0 : A0;
        uu.y = lh ? sB1 : A1;
        uu.z = lh ? B0  : sA0;
        uu.w = lh ? B1  : sA1;
        pfrag[s] = __builtin_bit_cast(half8, uu);
      }

      // O^T += mfma(V^T, P^T): oacc[dt] covers d in [dt*32, +32), q = l31
      __builtin_amdgcn_s_setprio(1);
#pragma unroll
      for (int dt = 0; dt < 4; ++dt) {
        int d = dt*32 + l31;
        const char* vbase = Vbase + (d >> 1)*256;
        int swv = l31 >> 1;
        int cbase = (d & 1) << 3;
#pragma unroll
        for (int s = 0; s < 4; ++s) {
          half8 vf = *(const half8*)(vbase + (((cbase + s*2 + lh) ^ swv) << 4));
          oacc[dt] = __builtin_amdgcn_mfma_f32_32x32x16_f16(vf, pfrag[s], oacc[dt], 0, 0, 0);
        }
      }
      __builtin_amdgcn_s_setprio(0);
    }

    __builtin_amdgcn_s_barrier();
  }

  // ---- epilogue: O^T -> LDS (swizzled) -> coalesced global f16
  float inv = 1.f / l_;
  int q = w*32 + l31;
#pragma unroll
  for (int dt = 0; dt < 4; ++dt)
#pragma unroll
    for (int rq = 0; rq < 4; ++rq) {
      half4v o4;
#pragma unroll
      for (int j = 0; j < 4; ++j) o4[j] = (_Float16)(oacc[dt][rq*4+j] * inv);
      int off = q*256 + ((dt*64 + rq*16 + lh*8) ^ ((q & 15) << 4));
      *(half4v*)(SMEM + off) = o4;
    }
  __syncthreads();
  int qr = tid >> 1, hf = tid & 1;
  size_t gbase = ((size_t)(b*S_ + qb*128 + qr))*D_ + h*128 + hf*64;
#pragma unroll
  for (int j = 0; j < 8; ++j) {
    int c = hf*8 + j;
    half8 vv = *(const half8*)(SMEM + qr*256 + ((c ^ (qr & 15)) << 4));
    *(half8*)(Ob + gbase + j*8) = vv;
  }
}

// ---------------- launch ----------------

extern "C" void kernel_launch(void* const* d_in, const int* in_sizes, int n_in,
                              void* d_out, int out_size, void* d_ws, size_t ws_size,
                              hipStream_t stream) {
  const float* x   = (const float*)d_in[0];
  const float* Wq  = (const float*)d_in[1];
  const float* Wk  = (const float*)d_in[2];
  const float* Wv  = (const float*)d_in[3];
  const float* Wo  = (const float*)d_in[4];
  const float* bo  = (const float*)d_in[5];
  const float* pol = (const float*)d_in[6];
  const float* mw  = (const float*)d_in[7];
  float* out = (float*)d_out;

  char* p = (char*)d_ws;
  auto take = [&](size_t bytes) { char* r = p; p += (bytes + 255) & ~(size_t)255; return r; };
  _Float16* xb   = (_Float16*)take((size_t)NT_*D_*2);
  _Float16* Wt   = (_Float16*)take((size_t)3*D_*D_*2);
  _Float16* Wot  = (_Float16*)take((size_t)D_*D_*2);
  _Float16* qkv  = (_Float16*)take((size_t)NT_*3*D_*2);
  _Float16* Qr   = (_Float16*)take((size_t)B_*H_*S_*HD_*2);
  _Float16* Kr   = (_Float16*)take((size_t)B_*H_*S_*HD_*2);
  _Float16* Vtb  = (_Float16*)take((size_t)B_*H_*S_*HD_*2);
  _Float16* Ob   = (_Float16*)take((size_t)NT_*D_*2);
  float* cost = (float*)take((size_t)S_*64*4);
  float* sint = (float*)take((size_t)S_*64*4);
  float* lmwb = (float*)take((size_t)B_*S_*4);

  cvt_f32_to_f16<<<(NT_*D_/4 + 255)/256, 256, 0, stream>>>(x, xb, NT_*D_/4);
  transpose_to_f16<<<dim3(64,64), dim3(32,8), 0, stream>>>(Wq, Wt,                    D_, D_);
  transpose_to_f16<<<dim3(64,64), dim3(32,8), 0, stream>>>(Wk, Wt +   (size_t)D_*D_,  D_, D_);
  transpose_to_f16<<<dim3(64,64), dim3(32,8), 0, stream>>>(Wv, Wt + 2*(size_t)D_*D_,  D_, D_);
  transpose_to_f16<<<dim3(64,64), dim3(32,8), 0, stream>>>(Wo, Wot, D_, D_);
  prep_tables<<<512, 256, 0, stream>>>(mw, cost, sint, lmwb);

  gemm_f16<false><<<dim3(3*D_/128, NT_/128), 256, 0, stream>>>(xb, Wt, qkv, nullptr, NT_, 3*D_, D_);
  rope_qk<<<NT_, 256, 0, stream>>>(qkv, cost, sint, Qr, Kr);
  v_transpose<<<dim3(S_/64, HD_/32, B_*H_), 256, 0, stream>>>(qkv, Vtb);
  attn_kernel<<<B_*H_*(S_/128), 256, 0, stream>>>(Qr, Kr, Vtb, pol, lmwb, Ob);
  gemm_f16<true><<<dim3(D_/128, NT_/128), 256, 0, stream>>>(Ob, Wot, out, bo, NT_, D_, D_);
}

// Round 8
// 378.141 us; speedup vs baseline: 2.5505x; 2.5505x over previous
//
#include <hip/hip_runtime.h>
#include <hip/hip_bf16.h>
#include <math.h>

#define B_ 2
#define S_ 2048
#define D_ 2048
#define H_ 16
#define HD_ 128
#define NT_ (B_*S_)
#define GS_ 0.1f
#define LOG2E_ 1.4426950408889634f

typedef _Float16 half8 __attribute__((__vector_size__(16)));
typedef _Float16 half4v __attribute__((__vector_size__(8)));
typedef _Float16 half2v __attribute__((__vector_size__(4)));
typedef float f32x4 __attribute__((__vector_size__(16)));
typedef float f32x16 __attribute__((__vector_size__(64)));

#define VMCNT(n) asm volatile("s_waitcnt vmcnt(" #n ")" ::: "memory")
#define LGKMCNT0 asm volatile("s_waitcnt lgkmcnt(0)" ::: "memory")

__device__ __forceinline__ void gload_lds16(const void* g, void* s) {
  __builtin_amdgcn_global_load_lds(
      (const __attribute__((address_space(1))) unsigned int*)g,
      (__attribute__((address_space(3))) unsigned int*)s, 16, 0, 0);
}

// ---------------- prep kernels ----------------

__global__ void cvt_f32_to_f16(const float* __restrict__ in, _Float16* __restrict__ out, int n4) {
  int i = blockIdx.x * blockDim.x + threadIdx.x;
  if (i >= n4) return;
  float4 v = ((const float4*)in)[i];
  half4v o = { (_Float16)v.x, (_Float16)v.y, (_Float16)v.z, (_Float16)v.w };
  ((half4v*)out)[i] = o;
}

// out[c][r] = (f16) in[r][c]   (in: R x C fp32 row-major)
__global__ void transpose_to_f16(const float* __restrict__ in, _Float16* __restrict__ out, int R, int C) {
  __shared__ float t[32][33];
  int c0 = blockIdx.x*32, r0 = blockIdx.y*32;
  int tx = threadIdx.x, ty = threadIdx.y;
#pragma unroll
  for (int j = 0; j < 32; j += 8)
    t[ty+j][tx] = in[(size_t)(r0+ty+j)*C + c0+tx];
  __syncthreads();
#pragma unroll
  for (int j = 0; j < 32; j += 8)
    out[(size_t)(c0+ty+j)*R + r0+tx] = (_Float16)t[tx][ty+j];
}

__global__ void prep_tables(const float* __restrict__ mw, float* __restrict__ cost,
                            float* __restrict__ sint, float* __restrict__ lmw) {
  int t = blockIdx.x*256 + threadIdx.x;
  if (t < S_*64) {
    int s = t >> 6, d = t & 63;
    float inv = (float)pow(10000.0, -(double)(2*d)/(double)HD_);
    float f = (float)s * inv;
    cost[t] = cosf(f);
    sint[t] = sinf(f);
  }
  // pre-scaled by log2e (consumed only by attn, which works in exp2 domain)
  if (t < B_*S_) lmw[t] = log1pf(mw[t]*GS_ + 1e-8f) * LOG2E_;
}

// ---------------- GEMM (R1 structure, 128x128, 4 waves, 3-4 blocks/CU) ----------------

template<bool F32OUT>
__global__ __launch_bounds__(256) void gemm_f16(
    const _Float16* __restrict__ A, const _Float16* __restrict__ Bt,
    void* __restrict__ Cout, const float* __restrict__ bias,
    int M, int N, int K)
{
  __shared__ __align__(16) _Float16 As[128*64];
  __shared__ __align__(16) _Float16 Bs[128*64];
  int n0 = blockIdx.x*128, m0 = blockIdx.y*128;
  int tid = threadIdx.x;
  int w = tid >> 6, l = tid & 63;
  int lhi = l >> 4, llo = l & 15;
  int wr = w >> 1, wc = w & 1;
  const f32x4 fz = {0.f,0.f,0.f,0.f};
  f32x4 acc[4][4];
#pragma unroll
  for (int i = 0; i < 4; ++i)
#pragma unroll
    for (int j = 0; j < 4; ++j) acc[i][j] = fz;

  for (int kt = 0; kt < K; kt += 64) {
#pragma unroll
    for (int i = 0; i < 4; ++i) {
      int sid = i*256 + tid;
      int row = sid >> 3;
      int c   = (sid & 7) ^ (row & 7);
      gload_lds16(A  + (size_t)(m0+row)*K + kt + c*8, (char*)As + (size_t)(i*256 + w*64)*16);
      gload_lds16(Bt + (size_t)(n0+row)*K + kt + c*8, (char*)Bs + (size_t)(i*256 + w*64)*16);
    }
    __syncthreads();
#pragma unroll
    for (int kk = 0; kk < 2; ++kk) {
      half8 a[4], b[4];
#pragma unroll
      for (int mi = 0; mi < 4; ++mi) {
        int row = wr*64 + mi*16 + llo;
        int ch = (kk*4 + lhi) ^ (row & 7);
        a[mi] = *(const half8*)((const char*)As + row*128 + ch*16);
      }
#pragma unroll
      for (int ni = 0; ni < 4; ++ni) {
        int row = wc*64 + ni*16 + llo;
        int ch = (kk*4 + lhi) ^ (row & 7);
        b[ni] = *(const half8*)((const char*)Bs + row*128 + ch*16);
      }
#pragma unroll
      for (int mi = 0; mi < 4; ++mi)
#pragma unroll
        for (int ni = 0; ni < 4; ++ni)
          acc[mi][ni] = __builtin_amdgcn_mfma_f32_16x16x32_f16(a[mi], b[ni], acc[mi][ni], 0, 0, 0);
    }
    __syncthreads();
  }
#pragma unroll
  for (int mi = 0; mi < 4; ++mi)
#pragma unroll
    for (int ni = 0; ni < 4; ++ni)
#pragma unroll
      for (int r = 0; r < 4; ++r) {
        int row = m0 + wr*64 + mi*16 + lhi*4 + r;
        int col = n0 + wc*64 + ni*16 + llo;
        if constexpr (F32OUT)
          ((float*)Cout)[(size_t)row*N + col] = acc[mi][ni][r] + bias[col];
        else
          ((_Float16*)Cout)[(size_t)row*N + col] = (_Float16)acc[mi][ni][r];
      }
}

// ---------------- RoPE + head reorder for Q,K ----------------
__global__ void rope_qk(const _Float16* __restrict__ qkv, const float* __restrict__ cost,
                        const float* __restrict__ sint, _Float16* __restrict__ Qr,
                        _Float16* __restrict__ Kr) {
  int token = blockIdx.x;
  int b = token >> 11, s = token & (S_-1);
  int t = threadIdx.x;
  int isk = t >> 7, u = t & 127;
  int hh = u >> 3, dd0 = (u & 7)*8;
  const _Float16* src = qkv + (size_t)token*(3*D_) + (size_t)isk*D_ + hh*128;
  half8 a  = *(const half8*)(src + dd0);
  half8 bb = *(const half8*)(src + 64 + dd0);
  half8 lo, hi;
#pragma unroll
  for (int j = 0; j < 8; ++j) {
    float c  = cost[s*64 + dd0 + j];
    float sn = sint[s*64 + dd0 + j];
    float x1 = (float)a[j], x2 = (float)bb[j];
    lo[j] = (_Float16)(x1*c - x2*sn);
    hi[j] = (_Float16)(x2*c + x1*sn);
  }
  _Float16* dst = (isk ? Kr : Qr) + ((size_t)(b*H_ + hh)*S_ + s)*HD_;
  *(half8*)(dst + dd0) = lo;
  *(half8*)(dst + 64 + dd0) = hi;
}

// ---------------- V transpose: qkv v-part -> Vt[b,h,d,s] ----------------
__global__ void v_transpose(const _Float16* __restrict__ qkv, _Float16* __restrict__ Vt) {
  __shared__ _Float16 tile[64][33];
  int st = blockIdx.x*64;
  int dt = blockIdx.y*32;
  int bh = blockIdx.z;
  int b = bh >> 4, h = bh & 15;
  int t = threadIdx.x;
  int s = t >> 2, dc = (t & 3)*8;
  half8 v = *(const half8*)(qkv + (size_t)(b*S_ + st + s)*(3*D_) + 2*D_ + h*128 + dt + dc);
#pragma unroll
  for (int j = 0; j < 8; ++j) tile[s][dc+j] = v[j];
  __syncthreads();
  int d = t >> 3, sc = (t & 7)*8;
  half8 o;
#pragma unroll
  for (int j = 0; j < 8; ++j) o[j] = tile[sc+j][d];
  *(half8*)(Vt + ((size_t)bh*HD_ + dt + d)*S_ + st + sc) = o;
}

// ---------------- flash attention: 4 waves x 32 q-rows, 32x32x16 MFMA ----------------
// R8 = R7 structure + __launch_bounds__(256) restored (R7's VGPR=64 default
// cap caused 1.8GB spill traffic; R5's identical declaration gave 172 VGPR,
// no spill). LDS 64KB (K dbuf 2x16K @0; V 16K @32768; bias 4x4K @49152)
// + VGPR<=256 -> 2 blocks/CU (25% occupancy, 2x R5).
__global__ __launch_bounds__(256) void attn_kernel(
    const _Float16* __restrict__ Qr, const _Float16* __restrict__ Kr,
    const _Float16* __restrict__ Vt, const float* __restrict__ policy,
    const float* __restrict__ lmw, _Float16* __restrict__ Ob)
{
  __shared__ __align__(16) char SMEM[65536];
  int bx = blockIdx.x;
  int qb = (S_/128) - 1 - (bx / (B_*H_));   // heavy tiles first
  int rem = bx % (B_*H_);
  int h = rem >> 1;
  int b = rem & 1;                          // b fastest -> policy L3 reuse
  int bh = b*H_ + h;
  const _Float16* Qb = Qr + (size_t)bh*S_*HD_;
  const _Float16* Kb = Kr + (size_t)bh*S_*HD_;
  const _Float16* Vb = Vt + (size_t)bh*HD_*S_;
  const float* pol = policy + (size_t)h*S_*S_;
  const float* lmb = lmw + b*S_;
  int tid = threadIdx.x;
  int w = tid >> 6, l = tid & 63;
  int l31 = l & 31, lh = l >> 5;
  int r8 = l >> 3, c8 = l & 7;
  int q0 = qb*128 + w*32;
  int gq = q0 + l31;
  char* Bw = SMEM + 49152 + w*4096;   // per-wave bias [g 0..15][q 0..31] 8B

  auto stageK = [&](int tt){
    char* dstb = SMEM + (size_t)(tt&1)*16384;
    int kv = tt*64;
#pragma unroll
    for (int i = 0; i < 4; ++i) {
      int sid = i*256 + tid;
      int krow = sid >> 4;
      int ck = (sid & 15) ^ (krow & 15);
      gload_lds16(Kb + (size_t)(kv+krow)*HD_ + ck*8, dstb + (size_t)(i*256 + w*64)*16);
    }
  };
  auto stageV = [&](int tt){
    char* dstb = SMEM + 32768;
    int kv = tt*64;
#pragma unroll
    for (int i = 0; i < 4; ++i) {
      int sid = i*256 + tid;
      int krow = sid >> 4;
      int ck = (sid & 15) ^ (krow & 15);
      int dv = krow*2 + (ck >> 3);
      gload_lds16(Vb + (size_t)dv*S_ + kv + (ck & 7)*8, dstb + (size_t)(i*256 + w*64)*16);
    }
  };

  const float qscale = 0.08838834764831845f * LOG2E_;  // 1/sqrt(128) * log2e
  half8 qf[8];
#pragma unroll
  for (int ds = 0; ds < 8; ++ds) {
    half8 qv = *(const half8*)(Qb + (size_t)gq*HD_ + ds*16 + lh*8);
#pragma unroll
    for (int e = 0; e < 8; ++e) qv[e] = (_Float16)((float)qv[e] * qscale);
    qf[ds] = qv;
  }

  f32x16 oacc[4];
#pragma unroll
  for (int i = 0; i < 4; ++i)
#pragma unroll
    for (int r = 0; r < 16; ++r) oacc[i][r] = 0.f;
  float m_ = -INFINITY, l_ = 0.f;
  const float GS2 = GS_ * LOG2E_;
  int nt = qb*2 + 2;

  // prologue: K(0)
  stageK(0);
  VMCNT(0);
  __builtin_amdgcn_sched_barrier(0);
  __builtin_amdgcn_s_barrier();

  for (int t = 0; t < nt; ++t) {
    int kv0 = t*64;
    const char* Kbase = SMEM + (size_t)(t&1)*16384;
    const char* Vbase = SMEM + 32768;
    bool pre = (t+1 < nt);
    bool act = (kv0 <= q0 + 31);

    // ---- issue: K(t+1), bias(t) (reg), V(t)
    if (pre) stageK(t+1);
    float4 pb[4][2], lm[2];
    if (act) {
#pragma unroll
      for (int ci = 0; ci < 2; ++ci) {
        lm[ci] = *(const float4*)(lmb + kv0 + ci*32 + c8*4);
#pragma unroll
        for (int ri = 0; ri < 4; ++ri)
          pb[ri][ci] = *(const float4*)(pol + (size_t)(q0 + ri*8 + r8)*S_ + kv0 + ci*32 + c8*4);
      }
    }
    stageV(t);

    // ---- S^T = mfma(K, Q): sacc[kh] covers k in [kh*32, +32), q = l31
    f32x16 sacc[2];
    if (act) {
#pragma unroll
      for (int kh = 0; kh < 2; ++kh)
#pragma unroll
        for (int r = 0; r < 16; ++r) sacc[kh][r] = 0.f;
      __builtin_amdgcn_s_setprio(1);
#pragma unroll
      for (int kh = 0; kh < 2; ++kh) {
        const char* kbase = Kbase + (kh*32 + l31)*256;
        int sw = l31 & 15;
#pragma unroll
        for (int ds = 0; ds < 8; ++ds) {
          half8 kf = *(const half8*)(kbase + (((ds*2 + lh) ^ sw) << 4));
          sacc[kh] = __builtin_amdgcn_mfma_f32_32x32x16_f16(kf, qf[ds], sacc[kh], 0, 0, 0);
        }
      }
      __builtin_amdgcn_s_setprio(0);
    }

    // ---- single gate: bias regs + V ready (K(t+1) drained early, harmless)
    VMCNT(0);
    __builtin_amdgcn_sched_barrier(0);

    if (act) {
      // bias build -> wave-private LDS [g][q], write ~4-way, read 2-way
#pragma unroll
      for (int ci = 0; ci < 2; ++ci)
#pragma unroll
        for (int ri = 0; ri < 4; ++ri) {
          float bx_ = fmaf(pb[ri][ci].x, GS2, lm[ci].x);
          float by_ = fmaf(pb[ri][ci].y, GS2, lm[ci].y);
          float bz_ = fmaf(pb[ri][ci].z, GS2, lm[ci].z);
          float bw_ = fmaf(pb[ri][ci].w, GS2, lm[ci].w);
          half2v h0 = __builtin_amdgcn_cvt_pkrtz(bx_, by_);
          half2v h1 = __builtin_amdgcn_cvt_pkrtz(bz_, bw_);
          half4v o4 = { h0[0], h0[1], h1[0], h1[1] };
          int g = ci*8 + c8;
          *(half4v*)(Bw + g*256 + (((ri*8 + r8) ^ (2*g)) & 31)*8) = o4;
        }
      LGKMCNT0;
      __builtin_amdgcn_sched_barrier(0);

      bool domask = (kv0 + 63 > q0);
#pragma unroll
      for (int kh = 0; kh < 2; ++kh)
#pragma unroll
        for (int rq = 0; rq < 4; ++rq) {
          int g = kh*8 + 2*rq + lh;
          half4v b4 = *(const half4v*)(Bw + g*256 + (((l31 ^ (2*g)) & 31)*8));
#pragma unroll
          for (int rm = 0; rm < 4; ++rm) {
            int r = rq*4 + rm;
            float v = sacc[kh][r] + (float)b4[rm];
            int gk = kv0 + kh*32 + rm + 8*rq + 4*lh;
            if (domask && gk > gq) v = -1e9f;
            sacc[kh][r] = v;
          }
        }

      float mx = -INFINITY;
#pragma unroll
      for (int kh = 0; kh < 2; ++kh)
#pragma unroll
        for (int r = 0; r < 16; ++r) mx = fmaxf(mx, sacc[kh][r]);
      mx = fmaxf(mx, __shfl_xor(mx, 32));
      bool skip = __all(mx - m_ <= 11.5f);   // defer-max (T13), log2 units
      if (!skip) {
        float mnew = fmaxf(m_, mx);
        float fct = exp2f(m_ - mnew);
        m_ = mnew;
        l_ *= fct;
#pragma unroll
        for (int i = 0; i < 4; ++i)
#pragma unroll
          for (int r = 0; r < 16; ++r) oacc[i][r] *= fct;
      }
      float rsum = 0.f;
#pragma unroll
      for (int kh = 0; kh < 2; ++kh)
#pragma unroll
        for (int r = 0; r < 16; ++r) {
          float pp = exp2f(sacc[kh][r] - m_);
          sacc[kh][r] = pp;
          rsum += pp;
        }
      rsum += __shfl_xor(rsum, 32);
      l_ += rsum;

      // P repack to fp16 PV B-fragments (in-register)
      half8 pfrag[4];
#pragma unroll
      for (int s = 0; s < 4; ++s) {
        int kh = s >> 1, rb = (s & 1)*8;
        unsigned A0 = __builtin_bit_cast(unsigned, __builtin_amdgcn_cvt_pkrtz(sacc[kh][rb+0], sacc[kh][rb+1]));
        unsigned A1 = __builtin_bit_cast(unsigned, __builtin_amdgcn_cvt_pkrtz(sacc[kh][rb+2], sacc[kh][rb+3]));
        unsigned B0 = __builtin_bit_cast(unsigned, __builtin_amdgcn_cvt_pkrtz(sacc[kh][rb+4], sacc[kh][rb+5]));
        unsigned B1 = __builtin_bit_cast(unsigned, __builtin_amdgcn_cvt_pkrtz(sacc[kh][rb+6], sacc[kh][rb+7]));
        unsigned sA0 = (unsigned)__shfl_xor((int)A0, 32);
        unsigned sA1 = (unsigned)__shfl_xor((int)A1, 32);
        unsigned sB0 = (unsigned)__shfl_xor((int)B0, 32);
        unsigned sB1 = (unsigned)__shfl_xor((int)B1, 32);
        uint4 uu;
        uu.x = lh ? sB0 : A0;
        uu.y = lh ? sB1 : A1;
        uu.z = lh ? B0  : sA0;
        uu.w = lh ? B1  : sA1;
        pfrag[s] = __builtin_bit_cast(half8, uu);
      }

      // O^T += mfma(V^T, P^T): oacc[dt] covers d in [dt*32, +32), q = l31
      __builtin_amdgcn_s_setprio(1);
#pragma unroll
      for (int dt = 0; dt < 4; ++dt) {
        int d = dt*32 + l31;
        const char* vbase = Vbase + (d >> 1)*256;
        int swv = l31 >> 1;
        int cbase = (d & 1) << 3;
#pragma unroll
        for (int s = 0; s < 4; ++s) {
          half8 vf = *(const half8*)(vbase + (((cbase + s*2 + lh) ^ swv) << 4));
          oacc[dt] = __builtin_amdgcn_mfma_f32_32x32x16_f16(vf, pfrag[s], oacc[dt], 0, 0, 0);
        }
      }
      __builtin_amdgcn_s_setprio(0);
    }

    __builtin_amdgcn_s_barrier();
  }

  // ---- epilogue: O^T -> LDS (swizzled) -> coalesced global f16
  float inv = 1.f / l_;
  int q = w*32 + l31;
#pragma unroll
  for (int dt = 0; dt < 4; ++dt)
#pragma unroll
    for (int rq = 0; rq < 4; ++rq) {
      half4v o4;
#pragma unroll
      for (int j = 0; j < 4; ++j) o4[j] = (_Float16)(oacc[dt][rq*4+j] * inv);
      int off = q*256 + ((dt*64 + rq*16 + lh*8) ^ ((q & 15) << 4));
      *(half4v*)(SMEM + off) = o4;
    }
  __syncthreads();
  int qr = tid >> 1, hf = tid & 1;
  size_t gbase = ((size_t)(b*S_ + qb*128 + qr))*D_ + h*128 + hf*64;
#pragma unroll
  for (int j = 0; j < 8; ++j) {
    int c = hf*8 + j;
    half8 vv = *(const half8*)(SMEM + qr*256 + ((c ^ (qr & 15)) << 4));
    *(half8*)(Ob + gbase + j*8) = vv;
  }
}

// ---------------- launch ----------------

extern "C" void kernel_launch(void* const* d_in, const int* in_sizes, int n_in,
                              void* d_out, int out_size, void* d_ws, size_t ws_size,
                              hipStream_t stream) {
  const float* x   = (const float*)d_in[0];
  const float* Wq  = (const float*)d_in[1];
  const float* Wk  = (const float*)d_in[2];
  const float* Wv  = (const float*)d_in[3];
  const float* Wo  = (const float*)d_in[4];
  const float* bo  = (const float*)d_in[5];
  const float* pol = (const float*)d_in[6];
  const float* mw  = (const float*)d_in[7];
  float* out = (float*)d_out;

  char* p = (char*)d_ws;
  auto take = [&](size_t bytes) { char* r = p; p += (bytes + 255) & ~(size_t)255; return r; };
  _Float16* xb   = (_Float16*)take((size_t)NT_*D_*2);
  _Float16* Wt   = (_Float16*)take((size_t)3*D_*D_*2);
  _Float16* Wot  = (_Float16*)take((size_t)D_*D_*2);
  _Float16* qkv  = (_Float16*)take((size_t)NT_*3*D_*2);
  _Float16* Qr   = (_Float16*)take((size_t)B_*H_*S_*HD_*2);
  _Float16* Kr   = (_Float16*)take((size_t)B_*H_*S_*HD_*2);
  _Float16* Vtb  = (_Float16*)take((size_t)B_*H_*S_*HD_*2);
  _Float16* Ob   = (_Float16*)take((size_t)NT_*D_*2);
  float* cost = (float*)take((size_t)S_*64*4);
  float* sint = (float*)take((size_t)S_*64*4);
  float* lmwb = (float*)take((size_t)B_*S_*4);

  cvt_f32_to_f16<<<(NT_*D_/4 + 255)/256, 256, 0, stream>>>(x, xb, NT_*D_/4);
  transpose_to_f16<<<dim3(64,64), dim3(32,8), 0, stream>>>(Wq, Wt,                    D_, D_);
  transpose_to_f16<<<dim3(64,64), dim3(32,8), 0, stream>>>(Wk, Wt +   (size_t)D_*D_,  D_, D_);
  transpose_to_f16<<<dim3(64,64), dim3(32,8), 0, stream>>>(Wv, Wt + 2*(size_t)D_*D_,  D_, D_);
  transpose_to_f16<<<dim3(64,64), dim3(32,8), 0, stream>>>(Wo, Wot, D_, D_);
  prep_tables<<<512, 256, 0, stream>>>(mw, cost, sint, lmwb);

  gemm_f16<false><<<dim3(3*D_/128, NT_/128), 256, 0, stream>>>(xb, Wt, qkv, nullptr, NT_, 3*D_, D_);
  rope_qk<<<NT_, 256, 0, stream>>>(qkv, cost, sint, Qr, Kr);
  v_transpose<<<dim3(S_/64, HD_/32, B_*H_), 256, 0, stream>>>(qkv, Vtb);
  attn_kernel<<<B_*H_*(S_/128), 256, 0, stream>>>(Qr, Kr, Vtb, pol, lmwb, Ob);
  gemm_f16<true><<<dim3(D_/128, NT_/128), 256, 0, stream>>>(Ob, Wot, out, bo, NT_, D_, D_);
}